// Round 2
// baseline (177.288 us; speedup 1.0000x reference)
//
#include <hip/hip_runtime.h>
#include <math.h>

#define NN 1024
#define CC 256
#define TT 64

// ---------------- kernel 1: fused time-mean + row norm ----------------
// One WAVE per (tensor,row): 2048 waves = 512 blocks x 256 threads.
// Lane l owns float4 channel-group l (64 groups = C=256), loops over all
// T=64 time steps -> the mean needs NO cross-lane traffic, no LDS, no
// barrier. Loads are explicitly double-buffered (cur/nxt, 8 deep) so each
// wave keeps 8-16 float4 loads in flight regardless of the register
// allocator's appetite (old version: VGPR=32 -> ~5 in flight -> 2.8 TB/s).
__global__ __launch_bounds__(256) void mean_norm_kernel(
    const float* __restrict__ in0, const float* __restrict__ in1,
    float* __restrict__ x, float* __restrict__ y,
    float* __restrict__ nx, float* __restrict__ ny) {
  int wid = (blockIdx.x << 2) | (threadIdx.x >> 6);   // 0..2047
  int lane = threadIdx.x & 63;
  int m = wid >> 10;
  int n = wid & (NN - 1);
  const float4* src = (const float4*)((m ? in1 : in0) + (size_t)n * (TT * CC)) + lane;
  float* xo = m ? y : x;
  float* no = m ? ny : nx;

  float4 a0 = make_float4(0.f, 0.f, 0.f, 0.f);
  float4 a1 = make_float4(0.f, 0.f, 0.f, 0.f);
  float4 cur[8], nxt[8];
  #pragma unroll
  for (int t = 0; t < 8; ++t) cur[t] = src[(size_t)t * (CC / 4)];
  #pragma unroll
  for (int b = 0; b < 8; ++b) {
    if (b < 7) {
      #pragma unroll
      for (int t = 0; t < 8; ++t) nxt[t] = src[(size_t)((b + 1) * 8 + t) * (CC / 4)];
    }
    #pragma unroll
    for (int t = 0; t < 8; t += 2) {
      a0.x += cur[t].x;     a0.y += cur[t].y;     a0.z += cur[t].z;     a0.w += cur[t].w;
      a1.x += cur[t + 1].x; a1.y += cur[t + 1].y; a1.z += cur[t + 1].z; a1.w += cur[t + 1].w;
    }
    if (b < 7) {
      #pragma unroll
      for (int t = 0; t < 8; ++t) cur[t] = nxt[t];
    }
  }
  const float inv = 1.0f / TT;
  float4 s = make_float4((a0.x + a1.x) * inv, (a0.y + a1.y) * inv,
                         (a0.z + a1.z) * inv, (a0.w + a1.w) * inv);
  ((float4*)(xo + (size_t)n * CC))[lane] = s;
  float ssq = fmaf(s.x, s.x, fmaf(s.y, s.y, fmaf(s.z, s.z, s.w * s.w)));
  #pragma unroll
  for (int o = 32; o > 0; o >>= 1) ssq += __shfl_down(ssq, o, 64);
  if (lane == 0) no[n] = ssq;
}

// ---------------- kernel 2: fused pairwise-distance + reductions ----------------
// Grid (16,16): 64x64 tile, 512 threads = 2 K-groups x 256. Each group owns a
// 64-channel chunk pair half; both chunk buffers live in LDS simultaneously
// (128 KB), giving 8 waves/CU (2/SIMD) instead of the old 4 (1/SIMD).
// XOR-swizzled LDS tiles: element (row, g[float4]) stored at phys group
// g ^ ((row>>2)&7). All LDS ops are b128, <=2-way bank aliasing (free).
// Group-1 accumulators are combined into group-0 via a conflict-free LDS
// buffer (reusing tAX), then group 0 runs the identical epilogue.
__global__ __launch_bounds__(512) void dist_kernel(
    const float* __restrict__ x, const float* __restrict__ y,
    const float* __restrict__ nx, const float* __restrict__ ny,
    float* __restrict__ Rxp, float* __restrict__ Ryp,
    float* __restrict__ pab, float* __restrict__ paa, float* __restrict__ pbb) {
  __shared__ float4 tAX[2][64][16];
  __shared__ float4 tAY[2][64][16];
  __shared__ float4 tBX[2][64][16];
  __shared__ float4 tBY[2][64][16];
  __shared__ float redp[3][8];

  int tid = threadIdx.x;
  int kg = tid >> 8;             // K-group: waves 0-3 -> 0, waves 4-7 -> 1
  int s = tid & 255;             // id within group
  int tx = s & 15, ty = s >> 4;
  int ti = blockIdx.y * 64, tj = blockIdx.x * 64;

  float accx[4][4] = {};
  float accy[4][4] = {};

  const float4* gx = (const float4*)x;   // [row][64] float4 groups
  const float4* gy = (const float4*)y;

  #pragma unroll
  for (int ph = 0; ph < 2; ++ph) {       // phase ph stages chunks 2ph, 2ph+1
    if (ph) __syncthreads();             // protect LDS from previous compute
    #pragma unroll
    for (int s2 = 0; s2 < 4; ++s2) {
      int f4 = tid + s2 * 512;           // 0..2047
      int buf = f4 >> 10;                // which chunk buffer
      int idx = f4 & 1023;
      int r = idx >> 4;                  // 0..63
      int g = idx & 15;
      int pg = g ^ ((r >> 2) & 7);
      int col = (2 * ph + buf) * 16 + g; // global float4-group column
      tAX[buf][r][pg] = gx[(size_t)(ti + r) * 64 + col];
      tAY[buf][r][pg] = gy[(size_t)(ti + r) * 64 + col];
      tBX[buf][r][pg] = gx[(size_t)(tj + r) * 64 + col];
      tBY[buf][r][pg] = gy[(size_t)(tj + r) * 64 + col];
    }
    __syncthreads();
    #pragma unroll
    for (int g = 0; g < 16; ++g) {       // group kg computes on its own buffer
      float4 bxv[4], byv[4];
      int pgb = g ^ (tx & 7);
      #pragma unroll
      for (int q = 0; q < 4; ++q) {
        bxv[q] = tBX[kg][4 * tx + q][pgb];
        byv[q] = tBY[kg][4 * tx + q][pgb];
      }
      int pga = g ^ (ty & 7);
      #pragma unroll
      for (int p = 0; p < 4; ++p) {
        float4 ax = tAX[kg][4 * ty + p][pga];
        float4 ay = tAY[kg][4 * ty + p][pga];
        #pragma unroll
        for (int q = 0; q < 4; ++q) {
          accx[p][q] = fmaf(ax.w, bxv[q].w, fmaf(ax.z, bxv[q].z,
                       fmaf(ax.y, bxv[q].y, fmaf(ax.x, bxv[q].x, accx[p][q]))));
          accy[p][q] = fmaf(ay.w, byv[q].w, fmaf(ay.z, byv[q].z,
                       fmaf(ay.y, byv[q].y, fmaf(ay.x, byv[q].x, accy[p][q]))));
        }
      }
    }
  }

  // ---- combine group-1 partial Gram into group-0 (conflict-free layout) ----
  __syncthreads();
  float4* cb4 = (float4*)&tAX[0][0][0];  // 32 KB scratch = 8 slots x 256 thr
  if (kg == 1) {
    #pragma unroll
    for (int p = 0; p < 4; ++p) {
      cb4[p * 256 + s] = make_float4(accx[p][0], accx[p][1], accx[p][2], accx[p][3]);
      cb4[(4 + p) * 256 + s] = make_float4(accy[p][0], accy[p][1], accy[p][2], accy[p][3]);
    }
  }
  __syncthreads();

  float ab = 0.f, aa = 0.f, bb = 0.f;
  if (kg == 0) {
    #pragma unroll
    for (int p = 0; p < 4; ++p) {
      float4 v = cb4[p * 256 + s];
      accx[p][0] += v.x; accx[p][1] += v.y; accx[p][2] += v.z; accx[p][3] += v.w;
      float4 w = cb4[(4 + p) * 256 + s];
      accy[p][0] += w.x; accy[p][1] += w.y; accy[p][2] += w.z; accy[p][3] += w.w;
    }

    // epilogue: d = sqrt(max(ni+nj-2g,0)+1e-12); accumulate sums
    float nix[4], niy[4], njx[4], njy[4];
    #pragma unroll
    for (int p = 0; p < 4; ++p) { nix[p] = nx[ti + 4 * ty + p]; niy[p] = ny[ti + 4 * ty + p]; }
    #pragma unroll
    for (int q = 0; q < 4; ++q) { njx[q] = nx[tj + 4 * tx + q]; njy[q] = ny[tj + 4 * tx + q]; }

    #pragma unroll
    for (int p = 0; p < 4; ++p) {
      float rsx = 0.f, rsy = 0.f;
      #pragma unroll
      for (int q = 0; q < 4; ++q) {
        float dxv = sqrtf(fmaxf(nix[p] + njx[q] - 2.f * accx[p][q], 0.f) + 1e-12f);
        float dyv = sqrtf(fmaxf(niy[p] + njy[q] - 2.f * accy[p][q], 0.f) + 1e-12f);
        ab = fmaf(dxv, dyv, ab);
        aa = fmaf(dxv, dxv, aa);
        bb = fmaf(dyv, dyv, bb);
        rsx += dxv; rsy += dyv;
      }
      // reduce row partial over the 16 tx-lanes of this ty-group
      #pragma unroll
      for (int o = 8; o > 0; o >>= 1) {
        rsx += __shfl_down(rsx, o, 16);
        rsy += __shfl_down(rsy, o, 16);
      }
      if (tx == 0) {
        Rxp[blockIdx.x * NN + ti + 4 * ty + p] = rsx;
        Ryp[blockIdx.x * NN + ti + 4 * ty + p] = rsy;
      }
    }
  }

  // block-level product partials over all 8 waves (group-1 waves carry zeros)
  #pragma unroll
  for (int o = 32; o > 0; o >>= 1) {
    ab += __shfl_down(ab, o, 64);
    aa += __shfl_down(aa, o, 64);
    bb += __shfl_down(bb, o, 64);
  }
  int wv = tid >> 6;
  if ((tid & 63) == 0) { redp[0][wv] = ab; redp[1][wv] = aa; redp[2][wv] = bb; }
  __syncthreads();
  if (tid == 0) {
    int blk = blockIdx.y * 16 + blockIdx.x;
    float sab = 0.f, saa = 0.f, sbb = 0.f;
    #pragma unroll
    for (int w = 0; w < 8; ++w) { sab += redp[0][w]; saa += redp[1][w]; sbb += redp[2][w]; }
    pab[blk] = sab; paa[blk] = saa; pbb[blk] = sbb;
  }
}

// ---------------- kernel 3: finalize ----------------
// <A,B> = S(DxDy) - (2/n) S(Rx.Ry) + Sx.Sy/n^2  (H idempotent, D symmetric)
__global__ __launch_bounds__(256) void finalize_kernel(
    const float* __restrict__ Rxp, const float* __restrict__ Ryp,
    const float* __restrict__ pab, const float* __restrict__ paa,
    const float* __restrict__ pbb, float* __restrict__ out) {
  int tid = threadIdx.x;
  const float4* rx4 = (const float4*)Rxp;
  const float4* ry4 = (const float4*)Ryp;
  float4 Rx = make_float4(0.f, 0.f, 0.f, 0.f);
  float4 Ry = make_float4(0.f, 0.f, 0.f, 0.f);
  #pragma unroll
  for (int b = 0; b < 16; ++b) {
    float4 v = rx4[b * 256 + tid];
    Rx.x += v.x; Rx.y += v.y; Rx.z += v.z; Rx.w += v.w;
    float4 w = ry4[b * 256 + tid];
    Ry.x += w.x; Ry.y += w.y; Ry.z += w.z; Ry.w += w.w;
  }
  double sx = (double)Rx.x + Rx.y + Rx.z + Rx.w;
  double sy = (double)Ry.x + Ry.y + Ry.z + Ry.w;
  double srr = (double)Rx.x * Ry.x + (double)Rx.y * Ry.y + (double)Rx.z * Ry.z + (double)Rx.w * Ry.w;
  double sxx = (double)Rx.x * Rx.x + (double)Rx.y * Rx.y + (double)Rx.z * Rx.z + (double)Rx.w * Rx.w;
  double syy = (double)Ry.x * Ry.x + (double)Ry.y * Ry.y + (double)Ry.z * Ry.z + (double)Ry.w * Ry.w;
  double ab = (double)pab[tid];   // 256 partials, 256 threads
  double aa = (double)paa[tid];
  double bb = (double)pbb[tid];
  #pragma unroll
  for (int o = 32; o > 0; o >>= 1) {
    sx += __shfl_down(sx, o, 64);  sy += __shfl_down(sy, o, 64);
    srr += __shfl_down(srr, o, 64); sxx += __shfl_down(sxx, o, 64);
    syy += __shfl_down(syy, o, 64); ab += __shfl_down(ab, o, 64);
    aa += __shfl_down(aa, o, 64);  bb += __shfl_down(bb, o, 64);
  }
  __shared__ double t[8][4];
  int lane = tid & 63, w = tid >> 6;
  if (lane == 0) {
    t[0][w] = sx; t[1][w] = sy; t[2][w] = srr; t[3][w] = sxx;
    t[4][w] = syy; t[5][w] = ab; t[6][w] = aa; t[7][w] = bb;
  }
  __syncthreads();
  if (tid == 0) {
    sx  = t[0][0] + t[0][1] + t[0][2] + t[0][3];
    sy  = t[1][0] + t[1][1] + t[1][2] + t[1][3];
    srr = t[2][0] + t[2][1] + t[2][2] + t[2][3];
    sxx = t[3][0] + t[3][1] + t[3][2] + t[3][3];
    syy = t[4][0] + t[4][1] + t[4][2] + t[4][3];
    ab  = t[5][0] + t[5][1] + t[5][2] + t[5][3];
    aa  = t[6][0] + t[6][1] + t[6][2] + t[6][3];
    bb  = t[7][0] + t[7][1] + t[7][2] + t[7][3];
    const double n = (double)NN, n2 = n * n;
    double AB = ab - (2.0 / n) * srr + sx * sy / n2;
    double AA = aa - (2.0 / n) * sxx + sx * sx / n2;
    double BB = bb - (2.0 / n) * syy + sy * sy / n2;
    double xy = AB / n2, xx = AA / n2, yy = BB / n2;
    double r = xy / sqrt(xx * yy + 1e-9);
    out[0] = (float)(1.0 - r);
  }
}

extern "C" void kernel_launch(void* const* d_in, const int* in_sizes, int n_in,
                              void* d_out, int out_size, void* d_ws, size_t ws_size,
                              hipStream_t stream) {
  const float* in0 = (const float*)d_in[0];   // output_1 (N,T,C) fp32
  const float* in1 = (const float*)d_in[1];   // feature  (N,T,C) fp32

  char* ws = (char*)d_ws;
  float* x   = (float*)(ws);                          // 1 MB
  float* y   = (float*)(ws + (1u << 20));             // 1 MB
  float* nx  = (float*)(ws + (2u << 20));             // 4 KB
  float* ny  = (float*)(ws + (2u << 20) + 4096);      // 4 KB
  float* Rxp = (float*)(ws + (2u << 20) + 8192);      // 64 KB (16x1024)
  float* Ryp = (float*)(ws + (2u << 20) + 8192 + 65536);        // 64 KB
  float* pab = (float*)(ws + (2u << 20) + 8192 + 2 * 65536);    // 1 KB
  float* paa = (float*)(ws + (2u << 20) + 8192 + 2 * 65536 + 1024);
  float* pbb = (float*)(ws + (2u << 20) + 8192 + 2 * 65536 + 2048);

  mean_norm_kernel<<<512, 256, 0, stream>>>(in0, in1, x, y, nx, ny);
  dist_kernel<<<dim3(16, 16), 512, 0, stream>>>(x, y, nx, ny, Rxp, Ryp, pab, paa, pbb);
  finalize_kernel<<<1, 256, 0, stream>>>(Rxp, Ryp, pab, paa, pbb, (float*)d_out);
}

// Round 3
// 171.573 us; speedup vs baseline: 1.0333x; 1.0333x over previous
//
#include <hip/hip_runtime.h>
#include <math.h>

#define NN 1024
#define CC 256
#define TT 64

// async global->LDS, 16B per lane. LDS dest is wave-uniform base + lane*16;
// global src is per-lane. Zero VGPR cost per outstanding load -> the
// compiler cannot collapse the pipeline (round-1/2 lesson: VGPR-staged
// double-buffers get rescheduled down to ~4 loads in flight).
#define AS1 __attribute__((address_space(1)))
#define AS3 __attribute__((address_space(3)))
static __device__ __forceinline__ void gload_lds16(const float* g, float4* l) {
  __builtin_amdgcn_global_load_lds((const AS1 void*)g, (AS3 void*)l, 16, 0, 0);
}

// ---------------- kernel 1: fused time-mean + row norm ----------------
// One block per (tensor,row): 2048 blocks x 256 threads. Wave w stages its
// 16 time-steps of the 64KB row into LDS via 16 back-to-back
// global_load_lds_dwordx4 (16KB in flight per wave, 64KB per block,
// 2 blocks/CU resident -> 128KB outstanding per CU). Consumption is gated
// by counted s_waitcnt vmcnt(12/8/4/0): loads retire in order, so each
// gate guarantees the next 4 t-rows are resident. No VGPR staging at all.
__global__ __launch_bounds__(256) void mean_norm_kernel(
    const float* __restrict__ in0, const float* __restrict__ in1,
    float* __restrict__ x, float* __restrict__ y,
    float* __restrict__ nx, float* __restrict__ ny) {
  __shared__ float4 buf[TT][CC / 4];   // 64 KB, [t][float4-group]
  __shared__ float4 red[3][64];
  int b = blockIdx.x;
  int m = b >> 10;
  int n = b & (NN - 1);
  const float* in = (m ? in1 : in0) + (size_t)n * (TT * CC);
  float* xo = m ? y : x;
  float* no = m ? ny : nx;
  int tid = threadIdx.x;
  int w = tid >> 6;          // wave id = time-quarter
  int lane = tid & 63;
  int tb = w * 16;           // this wave's first time-step

  // issue all 16 staging loads (1 KB each) before consuming anything
  #pragma unroll
  for (int i = 0; i < 16; ++i) {
    gload_lds16(in + (size_t)(tb + i) * CC + lane * 4, &buf[tb + i][0]);
  }

  float4 a0 = make_float4(0.f, 0.f, 0.f, 0.f);
  float4 a1 = make_float4(0.f, 0.f, 0.f, 0.f);

  // chunk 0: t = tb+0..3   (wait until <=12 outstanding -> oldest 4 done)
  asm volatile("s_waitcnt vmcnt(12)" ::: "memory");
  #pragma unroll
  for (int i = 0; i < 4; i += 2) {
    float4 v = buf[tb + i][lane];
    float4 u = buf[tb + i + 1][lane];
    a0.x += v.x; a0.y += v.y; a0.z += v.z; a0.w += v.w;
    a1.x += u.x; a1.y += u.y; a1.z += u.z; a1.w += u.w;
  }
  // chunk 1: t = tb+4..7
  asm volatile("s_waitcnt vmcnt(8)" ::: "memory");
  #pragma unroll
  for (int i = 4; i < 8; i += 2) {
    float4 v = buf[tb + i][lane];
    float4 u = buf[tb + i + 1][lane];
    a0.x += v.x; a0.y += v.y; a0.z += v.z; a0.w += v.w;
    a1.x += u.x; a1.y += u.y; a1.z += u.z; a1.w += u.w;
  }
  // chunk 2: t = tb+8..11
  asm volatile("s_waitcnt vmcnt(4)" ::: "memory");
  #pragma unroll
  for (int i = 8; i < 12; i += 2) {
    float4 v = buf[tb + i][lane];
    float4 u = buf[tb + i + 1][lane];
    a0.x += v.x; a0.y += v.y; a0.z += v.z; a0.w += v.w;
    a1.x += u.x; a1.y += u.y; a1.z += u.z; a1.w += u.w;
  }
  // chunk 3: t = tb+12..15
  asm volatile("s_waitcnt vmcnt(0)" ::: "memory");
  #pragma unroll
  for (int i = 12; i < 16; i += 2) {
    float4 v = buf[tb + i][lane];
    float4 u = buf[tb + i + 1][lane];
    a0.x += v.x; a0.y += v.y; a0.z += v.z; a0.w += v.w;
    a1.x += u.x; a1.y += u.y; a1.z += u.z; a1.w += u.w;
  }

  float4 p = make_float4(a0.x + a1.x, a0.y + a1.y, a0.z + a1.z, a0.w + a1.w);
  if (w) red[w - 1][lane] = p;
  __syncthreads();
  if (w == 0) {
    #pragma unroll
    for (int j = 0; j < 3; ++j) {
      float4 v = red[j][lane];
      p.x += v.x; p.y += v.y; p.z += v.z; p.w += v.w;
    }
    const float inv = 1.0f / TT;
    p.x *= inv; p.y *= inv; p.z *= inv; p.w *= inv;
    ((float4*)(xo + (size_t)n * CC))[lane] = p;
    float ssq = fmaf(p.x, p.x, fmaf(p.y, p.y, fmaf(p.z, p.z, p.w * p.w)));
    #pragma unroll
    for (int o = 32; o > 0; o >>= 1) ssq += __shfl_down(ssq, o, 64);
    if (lane == 0) no[n] = ssq;
  }
}

// ---------------- kernel 2: fused pairwise-distance + reductions ----------------
// Grid (16,16): 64x64 tile, 512 threads = 2 K-groups x 256. Each group owns a
// 64-channel chunk pair half; both chunk buffers live in LDS simultaneously
// (128 KB), giving 8 waves/CU (2/SIMD) instead of the old 4 (1/SIMD).
// XOR-swizzled LDS tiles: element (row, g[float4]) stored at phys group
// g ^ ((row>>2)&7). All LDS ops are b128, <=2-way bank aliasing (free).
// Group-1 accumulators are combined into group-0 via a conflict-free LDS
// buffer (reusing tAX), then group 0 runs the identical epilogue.
__global__ __launch_bounds__(512) void dist_kernel(
    const float* __restrict__ x, const float* __restrict__ y,
    const float* __restrict__ nx, const float* __restrict__ ny,
    float* __restrict__ Rxp, float* __restrict__ Ryp,
    float* __restrict__ pab, float* __restrict__ paa, float* __restrict__ pbb) {
  __shared__ float4 tAX[2][64][16];
  __shared__ float4 tAY[2][64][16];
  __shared__ float4 tBX[2][64][16];
  __shared__ float4 tBY[2][64][16];
  __shared__ float redp[3][8];

  int tid = threadIdx.x;
  int kg = tid >> 8;             // K-group: waves 0-3 -> 0, waves 4-7 -> 1
  int s = tid & 255;             // id within group
  int tx = s & 15, ty = s >> 4;
  int ti = blockIdx.y * 64, tj = blockIdx.x * 64;

  float accx[4][4] = {};
  float accy[4][4] = {};

  const float4* gx = (const float4*)x;   // [row][64] float4 groups
  const float4* gy = (const float4*)y;

  #pragma unroll
  for (int ph = 0; ph < 2; ++ph) {       // phase ph stages chunks 2ph, 2ph+1
    if (ph) __syncthreads();             // protect LDS from previous compute
    #pragma unroll
    for (int s2 = 0; s2 < 4; ++s2) {
      int f4 = tid + s2 * 512;           // 0..2047
      int buf = f4 >> 10;                // which chunk buffer
      int idx = f4 & 1023;
      int r = idx >> 4;                  // 0..63
      int g = idx & 15;
      int pg = g ^ ((r >> 2) & 7);
      int col = (2 * ph + buf) * 16 + g; // global float4-group column
      tAX[buf][r][pg] = gx[(size_t)(ti + r) * 64 + col];
      tAY[buf][r][pg] = gy[(size_t)(ti + r) * 64 + col];
      tBX[buf][r][pg] = gx[(size_t)(tj + r) * 64 + col];
      tBY[buf][r][pg] = gy[(size_t)(tj + r) * 64 + col];
    }
    __syncthreads();
    #pragma unroll
    for (int g = 0; g < 16; ++g) {       // group kg computes on its own buffer
      float4 bxv[4], byv[4];
      int pgb = g ^ (tx & 7);
      #pragma unroll
      for (int q = 0; q < 4; ++q) {
        bxv[q] = tBX[kg][4 * tx + q][pgb];
        byv[q] = tBY[kg][4 * tx + q][pgb];
      }
      int pga = g ^ (ty & 7);
      #pragma unroll
      for (int p = 0; p < 4; ++p) {
        float4 ax = tAX[kg][4 * ty + p][pga];
        float4 ay = tAY[kg][4 * ty + p][pga];
        #pragma unroll
        for (int q = 0; q < 4; ++q) {
          accx[p][q] = fmaf(ax.w, bxv[q].w, fmaf(ax.z, bxv[q].z,
                       fmaf(ax.y, bxv[q].y, fmaf(ax.x, bxv[q].x, accx[p][q]))));
          accy[p][q] = fmaf(ay.w, byv[q].w, fmaf(ay.z, byv[q].z,
                       fmaf(ay.y, byv[q].y, fmaf(ay.x, byv[q].x, accy[p][q]))));
        }
      }
    }
  }

  // ---- combine group-1 partial Gram into group-0 (conflict-free layout) ----
  __syncthreads();
  float4* cb4 = (float4*)&tAX[0][0][0];  // 32 KB scratch = 8 slots x 256 thr
  if (kg == 1) {
    #pragma unroll
    for (int p = 0; p < 4; ++p) {
      cb4[p * 256 + s] = make_float4(accx[p][0], accx[p][1], accx[p][2], accx[p][3]);
      cb4[(4 + p) * 256 + s] = make_float4(accy[p][0], accy[p][1], accy[p][2], accy[p][3]);
    }
  }
  __syncthreads();

  float ab = 0.f, aa = 0.f, bb = 0.f;
  if (kg == 0) {
    #pragma unroll
    for (int p = 0; p < 4; ++p) {
      float4 v = cb4[p * 256 + s];
      accx[p][0] += v.x; accx[p][1] += v.y; accx[p][2] += v.z; accx[p][3] += v.w;
      float4 w = cb4[(4 + p) * 256 + s];
      accy[p][0] += w.x; accy[p][1] += w.y; accy[p][2] += w.z; accy[p][3] += w.w;
    }

    // epilogue: d = sqrt(max(ni+nj-2g,0)+1e-12); accumulate sums
    float nix[4], niy[4], njx[4], njy[4];
    #pragma unroll
    for (int p = 0; p < 4; ++p) { nix[p] = nx[ti + 4 * ty + p]; niy[p] = ny[ti + 4 * ty + p]; }
    #pragma unroll
    for (int q = 0; q < 4; ++q) { njx[q] = nx[tj + 4 * tx + q]; njy[q] = ny[tj + 4 * tx + q]; }

    #pragma unroll
    for (int p = 0; p < 4; ++p) {
      float rsx = 0.f, rsy = 0.f;
      #pragma unroll
      for (int q = 0; q < 4; ++q) {
        float dxv = sqrtf(fmaxf(nix[p] + njx[q] - 2.f * accx[p][q], 0.f) + 1e-12f);
        float dyv = sqrtf(fmaxf(niy[p] + njy[q] - 2.f * accy[p][q], 0.f) + 1e-12f);
        ab = fmaf(dxv, dyv, ab);
        aa = fmaf(dxv, dxv, aa);
        bb = fmaf(dyv, dyv, bb);
        rsx += dxv; rsy += dyv;
      }
      // reduce row partial over the 16 tx-lanes of this ty-group
      #pragma unroll
      for (int o = 8; o > 0; o >>= 1) {
        rsx += __shfl_down(rsx, o, 16);
        rsy += __shfl_down(rsy, o, 16);
      }
      if (tx == 0) {
        Rxp[blockIdx.x * NN + ti + 4 * ty + p] = rsx;
        Ryp[blockIdx.x * NN + ti + 4 * ty + p] = rsy;
      }
    }
  }

  // block-level product partials over all 8 waves (group-1 waves carry zeros)
  #pragma unroll
  for (int o = 32; o > 0; o >>= 1) {
    ab += __shfl_down(ab, o, 64);
    aa += __shfl_down(aa, o, 64);
    bb += __shfl_down(bb, o, 64);
  }
  int wv = tid >> 6;
  if ((tid & 63) == 0) { redp[0][wv] = ab; redp[1][wv] = aa; redp[2][wv] = bb; }
  __syncthreads();
  if (tid == 0) {
    int blk = blockIdx.y * 16 + blockIdx.x;
    float sab = 0.f, saa = 0.f, sbb = 0.f;
    #pragma unroll
    for (int w = 0; w < 8; ++w) { sab += redp[0][w]; saa += redp[1][w]; sbb += redp[2][w]; }
    pab[blk] = sab; paa[blk] = saa; pbb[blk] = sbb;
  }
}

// ---------------- kernel 3: finalize ----------------
// <A,B> = S(DxDy) - (2/n) S(Rx.Ry) + Sx.Sy/n^2  (H idempotent, D symmetric)
__global__ __launch_bounds__(256) void finalize_kernel(
    const float* __restrict__ Rxp, const float* __restrict__ Ryp,
    const float* __restrict__ pab, const float* __restrict__ paa,
    const float* __restrict__ pbb, float* __restrict__ out) {
  int tid = threadIdx.x;
  const float4* rx4 = (const float4*)Rxp;
  const float4* ry4 = (const float4*)Ryp;
  float4 Rx = make_float4(0.f, 0.f, 0.f, 0.f);
  float4 Ry = make_float4(0.f, 0.f, 0.f, 0.f);
  #pragma unroll
  for (int b = 0; b < 16; ++b) {
    float4 v = rx4[b * 256 + tid];
    Rx.x += v.x; Rx.y += v.y; Rx.z += v.z; Rx.w += v.w;
    float4 w = ry4[b * 256 + tid];
    Ry.x += w.x; Ry.y += w.y; Ry.z += w.z; Ry.w += w.w;
  }
  double sx = (double)Rx.x + Rx.y + Rx.z + Rx.w;
  double sy = (double)Ry.x + Ry.y + Ry.z + Ry.w;
  double srr = (double)Rx.x * Ry.x + (double)Rx.y * Ry.y + (double)Rx.z * Ry.z + (double)Rx.w * Ry.w;
  double sxx = (double)Rx.x * Rx.x + (double)Rx.y * Rx.y + (double)Rx.z * Rx.z + (double)Rx.w * Rx.w;
  double syy = (double)Ry.x * Ry.x + (double)Ry.y * Ry.y + (double)Ry.z * Ry.z + (double)Ry.w * Ry.w;
  double ab = (double)pab[tid];   // 256 partials, 256 threads
  double aa = (double)paa[tid];
  double bb = (double)pbb[tid];
  #pragma unroll
  for (int o = 32; o > 0; o >>= 1) {
    sx += __shfl_down(sx, o, 64);  sy += __shfl_down(sy, o, 64);
    srr += __shfl_down(srr, o, 64); sxx += __shfl_down(sxx, o, 64);
    syy += __shfl_down(syy, o, 64); ab += __shfl_down(ab, o, 64);
    aa += __shfl_down(aa, o, 64);  bb += __shfl_down(bb, o, 64);
  }
  __shared__ double t[8][4];
  int lane = tid & 63, w = tid >> 6;
  if (lane == 0) {
    t[0][w] = sx; t[1][w] = sy; t[2][w] = srr; t[3][w] = sxx;
    t[4][w] = syy; t[5][w] = ab; t[6][w] = aa; t[7][w] = bb;
  }
  __syncthreads();
  if (tid == 0) {
    sx  = t[0][0] + t[0][1] + t[0][2] + t[0][3];
    sy  = t[1][0] + t[1][1] + t[1][2] + t[1][3];
    srr = t[2][0] + t[2][1] + t[2][2] + t[2][3];
    sxx = t[3][0] + t[3][1] + t[3][2] + t[3][3];
    syy = t[4][0] + t[4][1] + t[4][2] + t[4][3];
    ab  = t[5][0] + t[5][1] + t[5][2] + t[5][3];
    aa  = t[6][0] + t[6][1] + t[6][2] + t[6][3];
    bb  = t[7][0] + t[7][1] + t[7][2] + t[7][3];
    const double n = (double)NN, n2 = n * n;
    double AB = ab - (2.0 / n) * srr + sx * sy / n2;
    double AA = aa - (2.0 / n) * sxx + sx * sx / n2;
    double BB = bb - (2.0 / n) * syy + sy * sy / n2;
    double xy = AB / n2, xx = AA / n2, yy = BB / n2;
    double r = xy / sqrt(xx * yy + 1e-9);
    out[0] = (float)(1.0 - r);
  }
}

extern "C" void kernel_launch(void* const* d_in, const int* in_sizes, int n_in,
                              void* d_out, int out_size, void* d_ws, size_t ws_size,
                              hipStream_t stream) {
  const float* in0 = (const float*)d_in[0];   // output_1 (N,T,C) fp32
  const float* in1 = (const float*)d_in[1];   // feature  (N,T,C) fp32

  char* ws = (char*)d_ws;
  float* x   = (float*)(ws);                          // 1 MB
  float* y   = (float*)(ws + (1u << 20));             // 1 MB
  float* nx  = (float*)(ws + (2u << 20));             // 4 KB
  float* ny  = (float*)(ws + (2u << 20) + 4096);      // 4 KB
  float* Rxp = (float*)(ws + (2u << 20) + 8192);      // 64 KB (16x1024)
  float* Ryp = (float*)(ws + (2u << 20) + 8192 + 65536);        // 64 KB
  float* pab = (float*)(ws + (2u << 20) + 8192 + 2 * 65536);    // 1 KB
  float* paa = (float*)(ws + (2u << 20) + 8192 + 2 * 65536 + 1024);
  float* pbb = (float*)(ws + (2u << 20) + 8192 + 2 * 65536 + 2048);

  mean_norm_kernel<<<2 * NN, 256, 0, stream>>>(in0, in1, x, y, nx, ny);
  dist_kernel<<<dim3(16, 16), 512, 0, stream>>>(x, y, nx, ny, Rxp, Ryp, pab, paa, pbb);
  finalize_kernel<<<1, 256, 0, stream>>>(Rxp, Ryp, pab, paa, pbb, (float*)d_out);
}